// Round 5
// baseline (1257.904 us; speedup 1.0000x reference)
//
#include <hip/hip_runtime.h>
#include <hip/hip_bf16.h>
#include <math.h>

#define N_ITER 20
#define GROUPS 8
#define DIN 25
#define OC 64
#define IC 3
#define KK 25
#define H 224
#define W 224
#define B 8
#define CTOT (OC * GROUPS)   // 512

// ---------------- Stage 1: log-Sinkhorn on representations ----------------
// One block (64 threads = 1 wave) per group g. Matrix 25x25 in LDS.
__global__ void sinkhorn_kernel(const float* __restrict__ reps,
                                float* __restrict__ rep_out) {
    const int g = blockIdx.x;
    __shared__ float la[DIN][DIN];
    const int t = threadIdx.x;

    for (int idx = t; idx < DIN * DIN; idx += 64)
        la[idx / DIN][idx % DIN] = reps[g * DIN * DIN + idx];
    __syncthreads();

    for (int it = 0; it < N_ITER; ++it) {
        // rows (axis -1)
        if (t < DIN) {
            float m = -INFINITY;
            #pragma unroll
            for (int j = 0; j < DIN; ++j) m = fmaxf(m, la[t][j]);
            float s = 0.f;
            #pragma unroll
            for (int j = 0; j < DIN; ++j) s += expf(la[t][j] - m);
            const float lse = m + logf(s);
            #pragma unroll
            for (int j = 0; j < DIN; ++j) la[t][j] -= lse;
        }
        __syncthreads();
        // cols (axis -2)
        if (t < DIN) {
            float m = -INFINITY;
            #pragma unroll
            for (int j = 0; j < DIN; ++j) m = fmaxf(m, la[j][t]);
            float s = 0.f;
            #pragma unroll
            for (int j = 0; j < DIN; ++j) s += expf(la[j][t] - m);
            const float lse = m + logf(s);
            #pragma unroll
            for (int j = 0; j < DIN; ++j) la[j][t] -= lse;
        }
        __syncthreads();
    }

    for (int idx = t; idx < DIN * DIN; idx += 64)
        rep_out[g * DIN * DIN + idx] = expf(la[idx / DIN][idx % DIN]);
}

// ---------------- Stage 2: synthesize conv kernels -------------------------
// Kt[(i*25+n)*512 + c] = sum_m rep[g,n,m] * weight[o,i,m],  c = o*8+g
__global__ void synth_kernel(const float* __restrict__ rep,
                             const float* __restrict__ weight,
                             float* __restrict__ kt) {
    const int idx = blockIdx.x * 256 + threadIdx.x;
    if (idx >= CTOT * IC * KK) return;
    const int c = idx & (CTOT - 1);       // idx % 512
    const int innn = idx >> 9;            // i*25+n
    const int i = innn / KK, n = innn % KK;
    const int g = c & (GROUPS - 1), o = c >> 3;
    const float* __restrict__ rrow = rep + (g * DIN + n) * DIN;
    const float* __restrict__ wrow = weight + (o * IC + i) * KK;
    float s = 0.f;
    #pragma unroll
    for (int m = 0; m < KK; ++m) s = fmaf(rrow[m], wrow[m], s);
    kt[idx] = s;
}

// ---------------- Stage 3: direct conv -------------------------------------
// Block: 256 threads, spatial tile 32(w) x 8(h), one batch b, 8 consecutive
// output channels (cg*8 .. cg*8+7). x patch in LDS; weights via block-uniform
// (scalar) loads from Kt.
#define TW 32
#define TH 8
#define HALO_W (TW + 4)   // 36
#define HALO_H (TH + 4)   // 12

__launch_bounds__(256)
__global__ void conv_kernel(const float* __restrict__ x,
                            const float* __restrict__ kt,
                            const float* __restrict__ bias,
                            float* __restrict__ out) {
    const int tile = blockIdx.x;          // 0..195  (28 rows x 7 cols of tiles)
    const int cg   = blockIdx.y;          // 0..63   channel group of 8
    const int b    = blockIdx.z;          // 0..7
    const int ty0 = (tile / 7) * TH;
    const int tx0 = (tile % 7) * TW;

    __shared__ float xs[IC][HALO_H][HALO_W];

    const int t = threadIdx.x;
    const float* __restrict__ xb = x + b * IC * H * W;

    for (int l = t; l < IC * HALO_H * HALO_W; l += 256) {
        const int i  = l / (HALO_H * HALO_W);
        const int rm = l % (HALO_H * HALO_W);
        const int r  = rm / HALO_W;
        const int cc = rm % HALO_W;
        const int gy = ty0 + r - 2;
        const int gx = tx0 + cc - 2;
        float v = 0.f;
        if (gy >= 0 && gy < H && gx >= 0 && gx < W)
            v = xb[(i * H + gy) * W + gx];
        xs[i][r][cc] = v;
    }
    __syncthreads();

    const int tx = t & (TW - 1);
    const int ty = t >> 5;

    float acc[8];
    const float bv = bias[cg];            // o == cg for this channel group
    #pragma unroll
    for (int o = 0; o < 8; ++o) acc[o] = bv;

    const float* __restrict__ kwp = kt + cg * 8;

    #pragma unroll
    for (int i = 0; i < IC; ++i) {
        #pragma unroll
        for (int n = 0; n < KK; ++n) {
            const float xv = xs[i][ty + n / 5][tx + n % 5];
            const float* __restrict__ kk = kwp + (i * KK + n) * CTOT;
            #pragma unroll
            for (int o = 0; o < 8; ++o)
                acc[o] = fmaf(kk[o], xv, acc[o]);
        }
    }

    const int h = ty0 + ty, w = tx0 + tx;
    float* __restrict__ op = out + (((size_t)b * CTOT + cg * 8) * H + h) * W + w;
    #pragma unroll
    for (int o = 0; o < 8; ++o)
        op[(size_t)o * (H * W)] = acc[o];
}

extern "C" void kernel_launch(void* const* d_in, const int* in_sizes, int n_in,
                              void* d_out, int out_size, void* d_ws, size_t ws_size,
                              hipStream_t stream) {
    const float* x      = (const float*)d_in[0];
    const float* weight = (const float*)d_in[1];
    const float* reps   = (const float*)d_in[2];
    const float* bias   = (const float*)d_in[3];
    float* out = (float*)d_out;

    float* rep = (float*)d_ws;                              // 8*25*25 f32 = 20000 B
    float* kt  = (float*)((char*)d_ws + 20480);             // 512*75 f32 = 153600 B

    sinkhorn_kernel<<<dim3(GROUPS), dim3(64), 0, stream>>>(reps, rep);

    const int synth_total = CTOT * IC * KK;                 // 38400
    synth_kernel<<<dim3((synth_total + 255) / 256), dim3(256), 0, stream>>>(rep, weight, kt);

    dim3 grid((H / TH) * (W / TW), CTOT / 8, B);            // 196 x 64 x 8
    conv_kernel<<<grid, dim3(256), 0, stream>>>(x, kt, bias, out);
}